// Round 4
// baseline (312.922 us; speedup 1.0000x reference)
//
#include <hip/hip_runtime.h>
#include <stdint.h>

namespace {

constexpr int kB = 16;
constexpr int kC = 80;
constexpr int kNLev = 5;
constexpr int kTopK = 1000;
constexpr int kDets = 100;
constexpr int kNBins = 2048;
constexpr int kCap = 4096;
constexpr float kScoreT = 0.2f;
constexpr float kNmsT = 0.6f;
constexpr int kNTot = kNLev * kTopK;  // 5000
// blocks per image (256 locations each): L0:64, L1:16, L2:4, L3:1, L4:1 => 86
constexpr int kBlocksPerImg = 86;

struct LvlPtrs {
  const float* reg[5];
  const float* anc[5];
};

struct ClsPtrs {
  const float* cls[5];
  const float* ctr[5];
};

__device__ __forceinline__ float sigm(float x) {
  return 1.0f / (1.0f + expf(-x));
}

__device__ __forceinline__ void block_map(int c, int* L, int* ch) {
  if (c < 64)      { *L = 0; *ch = c; }
  else if (c < 80) { *L = 1; *ch = c - 64; }
  else if (c < 84) { *L = 2; *ch = c - 80; }
  else if (c < 85) { *L = 3; *ch = 0; }
  else             { *L = 4; *ch = 0; }
}

// ---- pass 1: histogram of scores per (b, level); thread-per-location ----
__global__ void __launch_bounds__(256)
khist_all(ClsPtrs CP, unsigned int* __restrict__ ghist) {
  const int b = blockIdx.x / kBlocksPerImg;
  const int c = blockIdx.x % kBlocksPerImg;
  int L, ch; block_map(c, &L, &ch);
  const int HW = 16384 >> (2 * L);
  const int loc = ch * 256 + (int)threadIdx.x;
  __shared__ unsigned int lh[kNBins];
  for (int i = threadIdx.x; i < kNBins; i += 256) lh[i] = 0;
  __syncthreads();
  if (loc < HW) {
    const float st = sigm(CP.ctr[L][(size_t)b * HW + loc]);
    const float4* p4 = reinterpret_cast<const float4*>(
        CP.cls[L] + ((size_t)b * HW + loc) * kC);
#pragma unroll 1
    for (int t = 0; t < 4; ++t) {
      // 5 independent 16B loads in flight (80 B/lane)
      float4 A0 = p4[t * 5 + 0];
      float4 A1 = p4[t * 5 + 1];
      float4 A2 = p4[t * 5 + 2];
      float4 A3 = p4[t * 5 + 3];
      float4 A4 = p4[t * 5 + 4];
      float f[20] = {A0.x, A0.y, A0.z, A0.w, A1.x, A1.y, A1.z, A1.w,
                     A2.x, A2.y, A2.z, A2.w, A3.x, A3.y, A3.z, A3.w,
                     A4.x, A4.y, A4.z, A4.w};
#pragma unroll
      for (int q = 0; q < 20; ++q) {
        float sc = sqrtf(sigm(f[q]) * st);
        if (sc > kScoreT) {
          int bin = (int)((sc - kScoreT) * 2560.0f);
          if (bin > kNBins - 1) bin = kNBins - 1;
          atomicAdd(&lh[bin], 1u);
        }
      }
    }
  }
  __syncthreads();
  unsigned int* gh = ghist + (size_t)(b * kNLev + L) * kNBins;
  for (int i = threadIdx.x; i < kNBins; i += 256)
    if (lh[i]) atomicAdd(&gh[i], lh[i]);
}

// ---- find cutoff bin: smallest bin with suffix-count >= TOPK ----
__global__ void kcutoff(const unsigned int* __restrict__ ghist, int* __restrict__ cutoff) {
  const int g = blockIdx.x;
  const unsigned int* h = ghist + (size_t)g * kNBins;
  __shared__ unsigned int lh[kNBins];
  __shared__ unsigned int tsum[256];
  for (int i = threadIdx.x; i < kNBins; i += 256) lh[i] = h[i];
  __syncthreads();
  unsigned int s = 0;
  for (int k = 0; k < kNBins / 256; ++k) s += lh[threadIdx.x * (kNBins / 256) + k];
  tsum[threadIdx.x] = s;
  __syncthreads();
  if (threadIdx.x == 0) {
    unsigned int acc = 0;
    for (int t = 255; t >= 0; --t) {
      if (acc + tsum[t] >= (unsigned)kTopK) {
        int c = 0;
        for (int bin = t * 8 + 7; bin >= t * 8; --bin) {
          acc += lh[bin];
          if (acc >= (unsigned)kTopK) { c = bin; break; }
        }
        cutoff[g] = c;
        return;
      }
      acc += tsum[t];
    }
    cutoff[g] = 0;
  }
}

// ---- pass 2: compact candidates in bins >= cutoff; thread-per-location ----
__global__ void __launch_bounds__(256)
kcompact_all(ClsPtrs CP, const int* __restrict__ cutoff, unsigned int* __restrict__ cnt,
             unsigned long long* __restrict__ cand) {
  const int b = blockIdx.x / kBlocksPerImg;
  const int c = blockIdx.x % kBlocksPerImg;
  int L, ch; block_map(c, &L, &ch);
  const int HW = 16384 >> (2 * L);
  const int loc = ch * 256 + (int)threadIdx.x;
  if (loc >= HW) return;  // wave-uniform (only the L4 block, whole waves)
  const int g = b * kNLev + L;
  const int cut = cutoff[g];
  const int lane = (int)(threadIdx.x & 63);
  const float st = sigm(CP.ctr[L][(size_t)b * HW + loc]);
  const float4* p4 = reinterpret_cast<const float4*>(
      CP.cls[L] + ((size_t)b * HW + loc) * kC);
  unsigned long long* gc = cand + (size_t)g * kCap;
#pragma unroll 1
  for (int t = 0; t < 4; ++t) {
    float4 A0 = p4[t * 5 + 0];
    float4 A1 = p4[t * 5 + 1];
    float4 A2 = p4[t * 5 + 2];
    float4 A3 = p4[t * 5 + 3];
    float4 A4 = p4[t * 5 + 4];
    float f[20] = {A0.x, A0.y, A0.z, A0.w, A1.x, A1.y, A1.z, A1.w,
                   A2.x, A2.y, A2.z, A2.w, A3.x, A3.y, A3.z, A3.w,
                   A4.x, A4.y, A4.z, A4.w};
#pragma unroll
    for (int q = 0; q < 20; ++q) {
      float sc = sqrtf(sigm(f[q]) * st);
      bool cond = false;
      if (sc > kScoreT) {
        int bin = (int)((sc - kScoreT) * 2560.0f);
        if (bin > kNBins - 1) bin = kNBins - 1;
        cond = (bin >= cut);
      }
      unsigned long long m = __ballot(cond);
      if (m != 0ull) {  // wave-uniform branch; rare (~0.6% of steps)
        int leader = (int)__builtin_ctzll(m);
        unsigned int base = 0;
        if (lane == leader)
          base = atomicAdd(&cnt[g], (unsigned int)__popcll(m));
        base = (unsigned int)__shfl((int)base, leader);
        if (cond) {
          unsigned int slot = base + (unsigned int)__popcll(m & ((1ull << lane) - 1ull));
          if (slot < (unsigned)kCap) {
            int e = loc * kC + t * 20 + q;
            unsigned int inv = 0xFFFFFFu - (((unsigned)L << 21) | (unsigned)e);
            gc[slot] = ((unsigned long long)__float_as_uint(sc) << 24) | inv;
          }
        }
      }
    }
  }
}

// ---- per-(b,level) rank-scatter: sorted top-1000 without a sort ----
__global__ void __launch_bounds__(1024)
krankl(const unsigned long long* __restrict__ cand, const unsigned int* __restrict__ cnt,
       unsigned long long* __restrict__ lvlsorted) {
  const int g = blockIdx.x;
  const int l = g % kNLev;
  __shared__ unsigned long long s[kCap];
  unsigned int nu = cnt[g];
  const int n = (nu > (unsigned)kCap) ? kCap : (int)nu;
  for (int i = threadIdx.x; i < n; i += 1024)
    s[i] = cand[(size_t)g * kCap + i];
  __syncthreads();
  // pad slots [n, kTopK): unique, tiny (score decodes to 0), descending in p
  for (int p = n + (int)threadIdx.x; p < kTopK; p += 1024)
    lvlsorted[(size_t)g * kTopK + p] =
        (unsigned long long)(kNTot - (l * kTopK + p));
  // rank-scatter: keys unique -> ranks are a permutation of [0, n)
  for (int i = threadIdx.x; i < n; i += 1024) {
    const unsigned long long ki = s[i];
    int r = 0;
#pragma unroll 8
    for (int j = 0; j < n; ++j) r += (s[j] > ki) ? 1 : 0;
    if (r < kTopK) lvlsorted[(size_t)g * kTopK + r] = ki;
  }
}

__device__ __forceinline__ void decode_key(unsigned long long key, int b, const LvlPtrs& P,
                                           float4* box, int* label_out, float* score_out) {
  float sc = __uint_as_float((unsigned int)(key >> 24));
  *score_out = sc;
  if (!(sc > kScoreT)) { *box = make_float4(0.f, 0.f, 0.f, 0.f); *label_out = -1; return; }
  unsigned int pk = 0xFFFFFFu - (unsigned int)(key & 0xFFFFFFu);
  int l = pk >> 21;
  int idx = pk & 0x1FFFFF;
  int pos = idx / kC;
  int label = idx - pos * kC;
  int hw = 16384 >> (2 * l);
  const float* rg = P.reg[l] + ((size_t)b * hw + pos) * 4;
  const float* an = P.anc[l] + (size_t)pos * 4;
  float a0 = an[0], a1 = an[1], a2 = an[2], a3 = an[3];
  float cx = (a0 + a2) * 0.5f, cy = (a1 + a3) * 0.5f;
  float w = a2 - a0, h = a3 - a1;
  float x0 = cx - rg[0] * w, y0 = cy - rg[1] * h;
  float x1 = cx + rg[2] * w, y1 = cy + rg[3] * h;
  x0 = fminf(fmaxf(x0, 0.f), 1024.f);
  y0 = fminf(fmaxf(y0, 0.f), 1024.f);
  x1 = fminf(fmaxf(x1, 0.f), 1024.f);
  y1 = fminf(fmaxf(y1, 0.f), 1024.f);
  *box = make_float4(x0, y0, x1, y1);
  *label_out = label;
}

// ---- merge 5 sorted lists into global desc order via rank; decode offset boxes ----
__global__ void krank(const unsigned long long* __restrict__ lvlsorted,
                      unsigned long long* __restrict__ skey,
                      float4* __restrict__ obox, LvlPtrs P) {
  int gid = blockIdx.x * blockDim.x + threadIdx.x;
  if (gid >= kB * kNTot) return;
  int b = gid / kNTot;
  int r0 = gid - b * kNTot;
  int a = r0 / kTopK, p = r0 - a * kTopK;
  const unsigned long long* base = lvlsorted + (size_t)b * kNTot;
  unsigned long long key = base[a * kTopK + p];
  int rank = p;
  for (int a2 = 0; a2 < kNLev; ++a2) {
    if (a2 == a) continue;
    const unsigned long long* lst = base + a2 * kTopK;
    int lo = 0, hi = kTopK;
    while (lo < hi) {
      int mid = (lo + hi) >> 1;
      if (lst[mid] > key) lo = mid + 1; else hi = mid;
    }
    rank += lo;
  }
  float4 box; int label; float sc;
  decode_key(key, b, P, &box, &label, &sc);
  float off = (sc > kScoreT) ? (float)label * 1025.0f : 0.0f;
  skey[(size_t)b * kNTot + rank] = key;
  obox[(size_t)b * kNTot + rank] =
      make_float4(box.x + off, box.y + off, box.z + off, box.w + off);
}

// ---- greedy NMS scan: one wave per image ----
__global__ void __launch_bounds__(64)
knms(const unsigned long long* __restrict__ skey, const float4* __restrict__ obox,
     LvlPtrs P, float* __restrict__ out) {
  const int b = blockIdx.x;
  const int lane = threadIdx.x;
  __shared__ float4 kbox[kDets];
  __shared__ float karea[kDets];
  __shared__ unsigned long long kkey[kDets];
  const unsigned long long* keys = skey + (size_t)b * kNTot;
  const float4* boxes = obox + (size_t)b * kNTot;
  int nkept = 0;
  for (int base = 0; base < kNTot && nkept < kDets; base += 64) {
    int j = base + lane;
    unsigned long long key = (j < kNTot) ? keys[j] : 0ull;
    float sc = __uint_as_float((unsigned int)(key >> 24));
    bool scval = (j < kNTot) && (sc > kScoreT);
    if (__ballot(scval) == 0ull) break;  // sorted desc: nothing valid remains
    float4 bx = make_float4(0.f, 0.f, 0.f, 0.f);
    if (scval) bx = boxes[j];
    float area = (bx.z - bx.x) * (bx.w - bx.y);
    bool alive = scval;
    for (int k = 0; k < nkept; ++k) {
      float4 kb = kbox[k];
      float xx1 = fmaxf(kb.x, bx.x), yy1 = fmaxf(kb.y, bx.y);
      float xx2 = fminf(kb.z, bx.z), yy2 = fminf(kb.w, bx.w);
      float inter = fmaxf(xx2 - xx1, 0.f) * fmaxf(yy2 - yy1, 0.f);
      float iou = inter / (area + karea[k] - inter + 1e-9f);
      if (iou > kNmsT) alive = false;
    }
    unsigned long long mask = __ballot(alive);
    while (mask != 0ull && nkept < kDets) {
      int lead = (int)__builtin_ctzll(mask);
      float lx = __shfl(bx.x, lead);
      float ly = __shfl(bx.y, lead);
      float lz = __shfl(bx.z, lead);
      float lw = __shfl(bx.w, lead);
      float la = __shfl(area, lead);
      unsigned int khi = (unsigned int)__shfl((int)(key >> 32), lead);
      unsigned int klo = (unsigned int)__shfl((int)(key & 0xFFFFFFFFull), lead);
      if (lane == 0) {
        kbox[nkept] = make_float4(lx, ly, lz, lw);
        karea[nkept] = la;
        kkey[nkept] = (((unsigned long long)khi) << 32) | (unsigned long long)klo;
      }
      __syncthreads();
      ++nkept;
      // suppress within chunk vs lead (lead suppresses itself: IoU == 1)
      float xx1 = fmaxf(lx, bx.x), yy1 = fmaxf(ly, bx.y);
      float xx2 = fminf(lz, bx.z), yy2 = fminf(lw, bx.w);
      float inter = fmaxf(xx2 - xx1, 0.f) * fmaxf(yy2 - yy1, 0.f);
      float iou = inter / (area + la - inter + 1e-9f);
      if (iou > kNmsT) alive = false;
      mask = __ballot(alive);
    }
  }
  // outputs: boxes [B,100,4] | scores [B,100] | labels [B,100]
  for (int s = lane; s < kDets; s += 64) {
    float4 bo = make_float4(0.f, 0.f, 0.f, 0.f);
    float so = 0.f, lo = -1.f;
    if (s < nkept) {
      float4 box; int label; float sc;
      decode_key(kkey[s], b, P, &box, &label, &sc);
      bo = box; so = sc; lo = (float)label;
    }
    size_t bi = (size_t)b * kDets + s;
    out[bi * 4 + 0] = bo.x;
    out[bi * 4 + 1] = bo.y;
    out[bi * 4 + 2] = bo.z;
    out[bi * 4 + 3] = bo.w;
    out[(size_t)kB * kDets * 4 + bi] = so;
    out[(size_t)kB * kDets * 5 + bi] = lo;
  }
}

}  // namespace

extern "C" void kernel_launch(void* const* d_in, const int* in_sizes, int n_in,
                              void* d_out, int out_size, void* d_ws, size_t ws_size,
                              hipStream_t stream) {
  ClsPtrs CP; LvlPtrs P;
  for (int l = 0; l < 5; ++l) {
    CP.cls[l] = (const float*)d_in[4 * l + 0];
    CP.ctr[l] = (const float*)d_in[4 * l + 1];
    P.reg[l]  = (const float*)d_in[4 * l + 2];
    P.anc[l]  = (const float*)d_in[4 * l + 3];
  }

  char* w = (char*)d_ws;
  unsigned int* hist = (unsigned int*)w;          w += (size_t)80 * kNBins * 4;  // 655360
  int* cutoff = (int*)w;                          w += 80 * 4;
  unsigned int* cnt = (unsigned int*)w;           w += 80 * 4;
  unsigned long long* cand = (unsigned long long*)w;      w += (size_t)80 * kCap * 8;
  unsigned long long* lvlsorted = (unsigned long long*)w; w += (size_t)80 * kTopK * 8;
  unsigned long long* skeyp = (unsigned long long*)w;     w += (size_t)kB * kNTot * 8;
  float4* oboxp = (float4*)w;                     w += (size_t)kB * kNTot * 16;

  // zero hist + cutoff + cnt (contiguous)
  hipMemsetAsync(hist, 0, (size_t)80 * kNBins * 4 + 80 * 8, stream);

  khist_all<<<kB * kBlocksPerImg, 256, 0, stream>>>(CP, hist);

  kcutoff<<<80, 256, 0, stream>>>(hist, cutoff);

  kcompact_all<<<kB * kBlocksPerImg, 256, 0, stream>>>(CP, cutoff, cnt, cand);

  krankl<<<80, 1024, 0, stream>>>(cand, cnt, lvlsorted);

  int rblocks = (kB * kNTot + 255) / 256;
  krank<<<rblocks, 256, 0, stream>>>(lvlsorted, skeyp, oboxp, P);

  knms<<<kB, 64, 0, stream>>>(skeyp, oboxp, P, (float*)d_out);
}

// Round 5
// 276.719 us; speedup vs baseline: 1.1308x; 1.1308x over previous
//
#include <hip/hip_runtime.h>
#include <stdint.h>

namespace {

constexpr int kB = 16;
constexpr int kC = 80;
constexpr int kNLev = 5;
constexpr int kTopK = 1000;
constexpr int kDets = 100;
constexpr int kNBins = 512;
constexpr int kCap = 6144;
constexpr float kScoreT = 0.2f;
constexpr float kNmsT = 0.6f;
constexpr int kChunk = 16384;
constexpr int kNTot = kNLev * kTopK;  // 5000
// chunks per image (16384 elems): L0:80, L1:20, L2:5, L3:2, L4:1 => 108
constexpr int kChunksPerImg = 108;
constexpr int kLvlChunk0[5] = {0, 80, 100, 105, 107};
constexpr int kLvlNChunk[5] = {80, 20, 5, 2, 1};

struct LvlPtrs {
  const float* reg[5];
  const float* anc[5];
};

struct ClsPtrs {
  const float* cls[5];
  const float* ctr[5];
};

// precise sigmoid — must match rounds 1-4 / XLA bits for stored keys
__device__ __forceinline__ float sigm(float x) {
  return 1.0f / (1.0f + expf(-x));
}
// fast sigmoid for selection only (v_exp + v_rcp)
__device__ __forceinline__ float sigm_fast(float x) {
  return __builtin_amdgcn_rcpf(1.0f + __expf(-x));
}

__device__ __forceinline__ void chunk_map(int c, int* L, int* ch) {
  if (c < 80)       { *L = 0; *ch = c; }
  else if (c < 100) { *L = 1; *ch = c - 80; }
  else if (c < 105) { *L = 2; *ch = c - 100; }
  else if (c < 107) { *L = 3; *ch = c - 105; }
  else              { *L = 4; *ch = 0; }
}

// ---- pass 1: approx-score histogram -> per-block partial (no atomics) ----
__global__ void __launch_bounds__(256)
khist_all(ClsPtrs CP, unsigned int* __restrict__ ph) {
  const int b = blockIdx.x / kChunksPerImg;
  const int c = blockIdx.x % kChunksPerImg;
  int L, ch; chunk_map(c, &L, &ch);
  const int HW = 16384 >> (2 * L);
  const int N = HW * kC;
  const int start = ch * kChunk;
  const int end = (start + kChunk < N) ? (start + kChunk) : N;
  __shared__ unsigned int lh[kNBins];
  for (int i = threadIdx.x; i < kNBins; i += 256) lh[i] = 0;
  __syncthreads();
  const float* clsb = CP.cls[L] + (size_t)b * N;
  const float* ctrb = CP.ctr[L] + (size_t)b * HW;
  const int tid4 = (int)threadIdx.x * 4;
#pragma unroll 1
  for (int bb = 0; bb < 2; ++bb) {
    const int base = start + bb * 8192;
    float4 vf[8]; int ke[8]; bool kv[8];
#pragma unroll
    for (int k = 0; k < 8; ++k) {
      int e = base + k * 1024 + tid4;
      ke[k] = e; kv[k] = (e < end);
      if (kv[k]) vf[k] = *reinterpret_cast<const float4*>(clsb + e);
    }
#pragma unroll
    for (int k = 0; k < 8; ++k) {
      if (!kv[k]) continue;
      const int e = ke[k];
      const int loc0 = (int)((unsigned)e / 80u);
      const int c0 = e - loc0 * kC;
      int loc1 = loc0 + 1; if (loc1 >= HW) loc1 = HW - 1;
      const float st0 = sigm_fast(ctrb[loc0]);
      const float st1 = sigm_fast(ctrb[loc1]);
      const float f[4] = {vf[k].x, vf[k].y, vf[k].z, vf[k].w};
#pragma unroll
      for (int q = 0; q < 4; ++q) {
        float st = (c0 + q >= kC) ? st1 : st0;
        float sc = __builtin_amdgcn_sqrtf(sigm_fast(f[q]) * st);
        int bin = (int)((sc - kScoreT) * 640.0f);
        if (bin >= 0) {
          if (bin > kNBins - 1) bin = kNBins - 1;
          atomicAdd(&lh[bin], 1u);
        }
      }
    }
  }
  __syncthreads();
  unsigned int* dst = ph + (size_t)blockIdx.x * kNBins;
  for (int i = threadIdx.x; i < kNBins; i += 256) dst[i] = lh[i];
}

// ---- reduce partials, find cutoff bin (suffix >= TOPK) ----
__global__ void __launch_bounds__(256)
kcutoff(const unsigned int* __restrict__ ph, int* __restrict__ cutoff) {
  const int g = blockIdx.x;
  const int b = g / kNLev, L = g % kNLev;
  const unsigned int* base =
      ph + (size_t)(b * kChunksPerImg + kLvlChunk0[L]) * kNBins;
  const int nb = kLvlNChunk[L];
  __shared__ unsigned int lh[kNBins];
  unsigned int a0 = 0, a1 = 0;
  for (int j = 0; j < nb; ++j) {
    a0 += base[(size_t)j * kNBins + threadIdx.x];
    a1 += base[(size_t)j * kNBins + 256 + threadIdx.x];
  }
  lh[threadIdx.x] = a0;
  lh[256 + threadIdx.x] = a1;
  __syncthreads();
  if (threadIdx.x == 0) {
    unsigned int acc = 0; int cut = 0;
    for (int bin = kNBins - 1; bin >= 0; --bin) {
      acc += lh[bin];
      if (acc >= (unsigned)kTopK) { cut = bin; break; }
    }
    cutoff[g] = cut;
  }
}

// ---- pass 2: approx prefilter (relaxed 2 bins) -> exact key for survivors ----
__global__ void __launch_bounds__(256)
kcompact_all(ClsPtrs CP, const int* __restrict__ cutoff, unsigned int* __restrict__ cnt,
             unsigned long long* __restrict__ cand) {
  const int b = blockIdx.x / kChunksPerImg;
  const int c = blockIdx.x % kChunksPerImg;
  int L, ch; chunk_map(c, &L, &ch);
  const int HW = 16384 >> (2 * L);
  const int N = HW * kC;
  const int start = ch * kChunk;
  const int end = (start + kChunk < N) ? (start + kChunk) : N;
  const int g = b * kNLev + L;
  // relaxed threshold: cut-2 bins, floored just below 0.2
  float thr = kScoreT + (float)(cutoff[g] - 2) * (1.0f / 640.0f);
  if (thr < 0.199f) thr = 0.199f;
  const float* clsb = CP.cls[L] + (size_t)b * N;
  const float* ctrb = CP.ctr[L] + (size_t)b * HW;
  unsigned long long* gc = cand + (size_t)g * kCap;
  const int tid4 = (int)threadIdx.x * 4;
#pragma unroll 1
  for (int bb = 0; bb < 2; ++bb) {
    const int base = start + bb * 8192;
    float4 vf[8]; int ke[8]; bool kv[8];
#pragma unroll
    for (int k = 0; k < 8; ++k) {
      int e = base + k * 1024 + tid4;
      ke[k] = e; kv[k] = (e < end);
      if (kv[k]) vf[k] = *reinterpret_cast<const float4*>(clsb + e);
    }
#pragma unroll
    for (int k = 0; k < 8; ++k) {
      if (!kv[k]) continue;
      const int e = ke[k];
      const int loc0 = (int)((unsigned)e / 80u);
      const int c0 = e - loc0 * kC;
      int loc1 = loc0 + 1; if (loc1 >= HW) loc1 = HW - 1;
      const float t0 = ctrb[loc0];
      const float t1 = ctrb[loc1];
      const float st0 = sigm_fast(t0);
      const float st1 = sigm_fast(t1);
      const float f[4] = {vf[k].x, vf[k].y, vf[k].z, vf[k].w};
#pragma unroll
      for (int q = 0; q < 4; ++q) {
        const bool hi = (c0 + q >= kC);
        float st = hi ? st1 : st0;
        float sa = __builtin_amdgcn_sqrtf(sigm_fast(f[q]) * st);
        if (sa >= thr) {  // rare (~0.2%)
          float traw = hi ? t1 : t0;
          float sex = sqrtf(sigm(f[q]) * sigm(traw));  // exact, matches ref bits
          if (sex > kScoreT) {
            unsigned int slot = atomicAdd(&cnt[g], 1u);
            if (slot < (unsigned)kCap) {
              int ee = e + q;
              unsigned int inv = 0xFFFFFFu - (((unsigned)L << 21) | (unsigned)ee);
              gc[slot] = ((unsigned long long)__float_as_uint(sex) << 24) | inv;
            }
          }
        }
      }
    }
  }
}

// ---- per-(b,level) rank-scatter: sorted top-1000 without a sort ----
__global__ void __launch_bounds__(1024)
krankl(const unsigned long long* __restrict__ cand, const unsigned int* __restrict__ cnt,
       unsigned long long* __restrict__ lvlsorted) {
  const int g = blockIdx.x;
  const int l = g % kNLev;
  __shared__ unsigned long long s[kCap];
  unsigned int nu = cnt[g];
  const int n = (nu > (unsigned)kCap) ? kCap : (int)nu;
  for (int i = threadIdx.x; i < n; i += 1024)
    s[i] = cand[(size_t)g * kCap + i];
  __syncthreads();
  for (int p = n + (int)threadIdx.x; p < kTopK; p += 1024)
    lvlsorted[(size_t)g * kTopK + p] =
        (unsigned long long)(kNTot - (l * kTopK + p));
  for (int i = threadIdx.x; i < n; i += 1024) {
    const unsigned long long ki = s[i];
    int r = 0;
#pragma unroll 8
    for (int j = 0; j < n; ++j) r += (s[j] > ki) ? 1 : 0;
    if (r < kTopK) lvlsorted[(size_t)g * kTopK + r] = ki;
  }
}

__device__ __forceinline__ void decode_key(unsigned long long key, int b, const LvlPtrs& P,
                                           float4* box, int* label_out, float* score_out) {
  float sc = __uint_as_float((unsigned int)(key >> 24));
  *score_out = sc;
  if (!(sc > kScoreT)) { *box = make_float4(0.f, 0.f, 0.f, 0.f); *label_out = -1; return; }
  unsigned int pk = 0xFFFFFFu - (unsigned int)(key & 0xFFFFFFu);
  int l = pk >> 21;
  int idx = pk & 0x1FFFFF;
  int pos = idx / kC;
  int label = idx - pos * kC;
  int hw = 16384 >> (2 * l);
  const float* rg = P.reg[l] + ((size_t)b * hw + pos) * 4;
  const float* an = P.anc[l] + (size_t)pos * 4;
  float a0 = an[0], a1 = an[1], a2 = an[2], a3 = an[3];
  float cx = (a0 + a2) * 0.5f, cy = (a1 + a3) * 0.5f;
  float w = a2 - a0, h = a3 - a1;
  float x0 = cx - rg[0] * w, y0 = cy - rg[1] * h;
  float x1 = cx + rg[2] * w, y1 = cy + rg[3] * h;
  x0 = fminf(fmaxf(x0, 0.f), 1024.f);
  y0 = fminf(fmaxf(y0, 0.f), 1024.f);
  x1 = fminf(fmaxf(x1, 0.f), 1024.f);
  y1 = fminf(fmaxf(y1, 0.f), 1024.f);
  *box = make_float4(x0, y0, x1, y1);
  *label_out = label;
}

// ---- merge 5 sorted lists into global desc order via rank; decode offset boxes ----
__global__ void krank(const unsigned long long* __restrict__ lvlsorted,
                      unsigned long long* __restrict__ skey,
                      float4* __restrict__ obox, LvlPtrs P) {
  int gid = blockIdx.x * blockDim.x + threadIdx.x;
  if (gid >= kB * kNTot) return;
  int b = gid / kNTot;
  int r0 = gid - b * kNTot;
  int a = r0 / kTopK, p = r0 - a * kTopK;
  const unsigned long long* base = lvlsorted + (size_t)b * kNTot;
  unsigned long long key = base[a * kTopK + p];
  int rank = p;
  for (int a2 = 0; a2 < kNLev; ++a2) {
    if (a2 == a) continue;
    const unsigned long long* lst = base + a2 * kTopK;
    int lo = 0, hi = kTopK;
    while (lo < hi) {
      int mid = (lo + hi) >> 1;
      if (lst[mid] > key) lo = mid + 1; else hi = mid;
    }
    rank += lo;
  }
  float4 box; int label; float sc;
  decode_key(key, b, P, &box, &label, &sc);
  float off = (sc > kScoreT) ? (float)label * 1025.0f : 0.0f;
  skey[(size_t)b * kNTot + rank] = key;
  obox[(size_t)b * kNTot + rank] =
      make_float4(box.x + off, box.y + off, box.z + off, box.w + off);
}

// ---- greedy NMS scan: one wave per image ----
__global__ void __launch_bounds__(64)
knms(const unsigned long long* __restrict__ skey, const float4* __restrict__ obox,
     LvlPtrs P, float* __restrict__ out) {
  const int b = blockIdx.x;
  const int lane = threadIdx.x;
  __shared__ float4 kbox[kDets];
  __shared__ float karea[kDets];
  __shared__ unsigned long long kkey[kDets];
  const unsigned long long* keys = skey + (size_t)b * kNTot;
  const float4* boxes = obox + (size_t)b * kNTot;
  int nkept = 0;
  for (int base = 0; base < kNTot && nkept < kDets; base += 64) {
    int j = base + lane;
    unsigned long long key = (j < kNTot) ? keys[j] : 0ull;
    float sc = __uint_as_float((unsigned int)(key >> 24));
    bool scval = (j < kNTot) && (sc > kScoreT);
    if (__ballot(scval) == 0ull) break;
    float4 bx = make_float4(0.f, 0.f, 0.f, 0.f);
    if (scval) bx = boxes[j];
    float area = (bx.z - bx.x) * (bx.w - bx.y);
    bool alive = scval;
    for (int k = 0; k < nkept; ++k) {
      float4 kb = kbox[k];
      float xx1 = fmaxf(kb.x, bx.x), yy1 = fmaxf(kb.y, bx.y);
      float xx2 = fminf(kb.z, bx.z), yy2 = fminf(kb.w, bx.w);
      float inter = fmaxf(xx2 - xx1, 0.f) * fmaxf(yy2 - yy1, 0.f);
      float iou = inter / (area + karea[k] - inter + 1e-9f);
      if (iou > kNmsT) alive = false;
    }
    unsigned long long mask = __ballot(alive);
    while (mask != 0ull && nkept < kDets) {
      int lead = (int)__builtin_ctzll(mask);
      float lx = __shfl(bx.x, lead);
      float ly = __shfl(bx.y, lead);
      float lz = __shfl(bx.z, lead);
      float lw = __shfl(bx.w, lead);
      float la = __shfl(area, lead);
      unsigned int khi = (unsigned int)__shfl((int)(key >> 32), lead);
      unsigned int klo = (unsigned int)__shfl((int)(key & 0xFFFFFFFFull), lead);
      if (lane == 0) {
        kbox[nkept] = make_float4(lx, ly, lz, lw);
        karea[nkept] = la;
        kkey[nkept] = (((unsigned long long)khi) << 32) | (unsigned long long)klo;
      }
      __syncthreads();
      ++nkept;
      float xx1 = fmaxf(lx, bx.x), yy1 = fmaxf(ly, bx.y);
      float xx2 = fminf(lz, bx.z), yy2 = fminf(lw, bx.w);
      float inter = fmaxf(xx2 - xx1, 0.f) * fmaxf(yy2 - yy1, 0.f);
      float iou = inter / (area + la - inter + 1e-9f);
      if (iou > kNmsT) alive = false;
      mask = __ballot(alive);
    }
  }
  for (int s = lane; s < kDets; s += 64) {
    float4 bo = make_float4(0.f, 0.f, 0.f, 0.f);
    float so = 0.f, lo = -1.f;
    if (s < nkept) {
      float4 box; int label; float sc;
      decode_key(kkey[s], b, P, &box, &label, &sc);
      bo = box; so = sc; lo = (float)label;
    }
    size_t bi = (size_t)b * kDets + s;
    out[bi * 4 + 0] = bo.x;
    out[bi * 4 + 1] = bo.y;
    out[bi * 4 + 2] = bo.z;
    out[bi * 4 + 3] = bo.w;
    out[(size_t)kB * kDets * 4 + bi] = so;
    out[(size_t)kB * kDets * 5 + bi] = lo;
  }
}

}  // namespace

extern "C" void kernel_launch(void* const* d_in, const int* in_sizes, int n_in,
                              void* d_out, int out_size, void* d_ws, size_t ws_size,
                              hipStream_t stream) {
  ClsPtrs CP; LvlPtrs P;
  for (int l = 0; l < 5; ++l) {
    CP.cls[l] = (const float*)d_in[4 * l + 0];
    CP.ctr[l] = (const float*)d_in[4 * l + 1];
    P.reg[l]  = (const float*)d_in[4 * l + 2];
    P.anc[l]  = (const float*)d_in[4 * l + 3];
  }

  const int nblk = kB * kChunksPerImg;  // 1728

  char* w = (char*)d_ws;
  unsigned int* ph = (unsigned int*)w;            w += (size_t)nblk * kNBins * 4;  // 3.54 MB
  int* cutoff = (int*)w;                          w += 80 * 4;
  unsigned int* cnt = (unsigned int*)w;           w += 80 * 4;
  unsigned long long* cand = (unsigned long long*)w;      w += (size_t)80 * kCap * 8;
  unsigned long long* lvlsorted = (unsigned long long*)w; w += (size_t)80 * kTopK * 8;
  unsigned long long* skeyp = (unsigned long long*)w;     w += (size_t)kB * kNTot * 8;
  float4* oboxp = (float4*)w;                     w += (size_t)kB * kNTot * 16;

  // zero cutoff + cnt only (partials are plain-stored)
  hipMemsetAsync(cutoff, 0, 80 * 8, stream);

  khist_all<<<nblk, 256, 0, stream>>>(CP, ph);

  kcutoff<<<80, 256, 0, stream>>>(ph, cutoff);

  kcompact_all<<<nblk, 256, 0, stream>>>(CP, cutoff, cnt, cand);

  krankl<<<80, 1024, 0, stream>>>(cand, cnt, lvlsorted);

  int rblocks = (kB * kNTot + 255) / 256;
  krank<<<rblocks, 256, 0, stream>>>(lvlsorted, skeyp, oboxp, P);

  knms<<<kB, 64, 0, stream>>>(skeyp, oboxp, P, (float*)d_out);
}